// Round 2
// baseline (1260.479 us; speedup 1.0000x reference)
//
#include <hip/hip_runtime.h>
#include <math.h>

#pragma clang fp contract(off)

#define NBINS 36
#define PS 32

// One block = one patch. Faithful f32 replication of the numpy/XLA-CPU
// reference semantics:
//  - conv taps pre-scaled (exact pow2 products), summed ascending (kh,kw)
//  - mag = sqrt((gx*gx + gy*gy) + eps), no FMA contraction
//  - atan2 computed in f64, rounded to f32 (correctly-rounded f32 atan2)
//  - histogram: per-bin sequential add chain in pixel order, w0 pass then w1
//    pass (np.add.at semantics) — 36 lanes each scan all 1024 pixels
//  - smoothing left-to-right, first-occurrence argmax (strict >)
__global__ __launch_bounds__(256)
void patch_orient_kernel(const float* __restrict__ patches, float* __restrict__ out)
{
    __shared__ __align__(16) float tile[PS][PS];   // 4 KiB
    __shared__ __align__(16) float wt0[1024];      // 4 KiB
    __shared__ __align__(16) float wt1[1024];      // 4 KiB
    __shared__ __align__(16) int   bin0[1024];     // 4 KiB
    __shared__ __align__(16) int   bin1[1024];     // 4 KiB
    __shared__ float hsm[NBINS];

    const int t = threadIdx.x;
    const int b = blockIdx.x;
    const float* p = patches + (size_t)b * (PS * PS);

    // coalesced load: 256 threads x float4 = 4 KiB
    ((float4*)tile)[t] = ((const float4*)p)[t];
    __syncthreads();

    const int j  = t & 31;               // column
    const int i0 = (t >> 5) << 2;        // first of 4 rows this thread owns
    const int jm = (j == 0)  ? 0  : j - 1;
    const int jp = (j == 31) ? 31 : j + 1;

    const float TWO_PI = 6.2831853071795864769f;   // f32(2*pi) == 2*f32(pi)
    const float PI_F   = 3.14159265358979323846f;

    #pragma unroll
    for (int r = 0; r < 4; ++r) {
        const int row = i0 + r;
        const int rm = (row == 0)  ? 0  : row - 1;
        const int rp = (row == 31) ? 31 : row + 1;
        float A = tile[rm][jm],  B = tile[rm][j],  C = tile[rm][jp];
        float D = tile[row][jm],                   F = tile[row][jp];
        float G = tile[rp][jm],  H = tile[rp][j],  I = tile[rp][jp];

        // kx = [[-1,0,1],[-2,0,2],[-1,0,1]]/8 ; ky = kx.T ; correlation,
        // pre-scaled taps (products exact), ascending (kh,kw) accumulation.
        float gx = -0.125f * A;
        gx += 0.125f * C;
        gx += -0.25f  * D;
        gx += 0.25f   * F;
        gx += -0.125f * G;
        gx += 0.125f  * I;

        float gy = -0.125f * A;
        gy += -0.25f  * B;
        gy += -0.125f * C;
        gy += 0.125f  * G;
        gy += 0.25f   * H;
        gy += 0.125f  * I;

        float m1 = gx * gx;
        float m2 = gy * gy;
        float s  = m1 + m2;
        s = s + 1e-8f;
        float mag = sqrtf(s);                      // IEEE sqrt (no fast-math)

        float gxe = gx + 1e-8f;
        float at  = (float)atan2((double)gy, (double)gxe);  // CR f32 atan2
        float ori = at + TWO_PI;
        float obig = (36.0f * (ori + PI_F)) / TWO_PI;
        float bo0  = floorf(obig);
        float wo1  = obig - bo0;                   // exact (Sterbenz)

        int bi0 = (int)bo0;
        bi0 = ((bi0 % NBINS) + NBINS) % NBINS;     // true floored mod (handles 35.99999 & 72)
        int bi1 = (bi0 + 1) % NBINS;

        int px = row * 32 + j;
        wt0[px]  = (1.0f - wo1) * mag;
        wt1[px]  = wo1 * mag;
        bin0[px] = bi0;
        bin1[px] = bi1;
    }
    __syncthreads();

    // Exact np.add.at replication: bin k's accumulator receives its matching
    // w0's in pixel order, then its matching w1's in pixel order.
    if (t < NBINS) {
        float acc = 0.0f;
        {
            const int4*   b4 = (const int4*)bin0;
            const float4* w4 = (const float4*)wt0;
            for (int i = 0; i < 256; ++i) {
                int4 bb = b4[i]; float4 ww = w4[i];
                acc += (bb.x == t) ? ww.x : 0.0f;   // +0.0 adds are exact no-ops
                acc += (bb.y == t) ? ww.y : 0.0f;
                acc += (bb.z == t) ? ww.z : 0.0f;
                acc += (bb.w == t) ? ww.w : 0.0f;
            }
        }
        {
            const int4*   b4 = (const int4*)bin1;
            const float4* w4 = (const float4*)wt1;
            for (int i = 0; i < 256; ++i) {
                int4 bb = b4[i]; float4 ww = w4[i];
                acc += (bb.x == t) ? ww.x : 0.0f;
                acc += (bb.y == t) ? ww.y : 0.0f;
                acc += (bb.z == t) ? ww.z : 0.0f;
                acc += (bb.w == t) ? ww.w : 0.0f;
            }
        }
        hsm[t] = acc * (1.0f / 1024.0f);           // /npix, exact pow2
    }
    __syncthreads();

    if (t == 0) {
        float best = -1.0f; int bi = 0;
        #pragma unroll
        for (int i = 0; i < NBINS; ++i) {
            int im_ = (i == 0)         ? NBINS - 1 : i - 1;
            int ip_ = (i == NBINS - 1) ? 0         : i + 1;
            float s0 = 0.33f * hsm[im_];
            float s1 = 0.34f * hsm[i];
            float s2 = 0.33f * hsm[ip_];
            float sm = (s0 + s1) + s2;             // left-to-right, no FMA
            if (sm > best) { best = sm; bi = i; }  // first-occurrence argmax
        }
        float t1 = TWO_PI * (float)bi;
        float t2 = t1 / 36.0f;
        float t3 = t2 - PI_F;
        out[b] = -t3;
    }
}

extern "C" void kernel_launch(void* const* d_in, const int* in_sizes, int n_in,
                              void* d_out, int out_size, void* d_ws, size_t ws_size,
                              hipStream_t stream) {
    const float* patch = (const float*)d_in[0];
    float* out = (float*)d_out;
    const int B = in_sizes[0] / (PS * PS);   // 65536 patches
    patch_orient_kernel<<<B, 256, 0, stream>>>(patch, out);
}

// Round 3
// 854.257 us; speedup vs baseline: 1.4755x; 1.4755x over previous
//
#include <hip/hip_runtime.h>
#include <math.h>

#pragma clang fp contract(off)

#define NBINS 36
#define PS 32

// One block = one patch. Bit-exact replication of the numpy reference:
//  - conv taps pre-scaled (exact pow2 products), summed ascending (kh,kw)
//  - mag = sqrt((gx*gx + gy*gy) + eps), contraction off
//  - atan2 computed in f64, rounded to f32 (correctly-rounded f32 atan2)
//  - histogram: per-bin sequential add chain in pixel order, w0 pass then
//    w1 pass (np.add.at semantics). Round-3 change: instead of 36 lanes
//    scanning all 2048 items (3 VALU/item wave-wide), phase 1 records a
//    per-bin 1024-bit bitmap (atomicOr — set-building is order-free) and
//    each chain-lane walks only ITS matches via ctz (ascending pixel
//    order == exact chain order). b1 = b0+1 mod 36, so the w1 pass for
//    bin k walks bitmap row (k-1) mod 36 — one bitmap serves both passes.
__global__ __launch_bounds__(256)
void patch_orient_kernel(const float* __restrict__ patches, float* __restrict__ out)
{
    __shared__ __align__(16) float tile[PS][PS];        // 4 KiB
    __shared__ __align__(16) float wt0[1024];           // 4 KiB
    __shared__ __align__(16) float wt1[1024];           // 4 KiB
    __shared__ unsigned bm[32][NBINS];                  // 4.5 KiB: bm[word][bin]
    __shared__ float hsm[NBINS];

    const int t = threadIdx.x;
    const int b = blockIdx.x;
    const float* p = patches + (size_t)b * (PS * PS);

    // zero bitmaps (1152 words)
    #pragma unroll
    for (int i = t; i < 32 * NBINS; i += 256) ((unsigned*)bm)[i] = 0u;

    // coalesced load: 256 threads x float4 = 4 KiB
    ((float4*)tile)[t] = ((const float4*)p)[t];
    __syncthreads();

    // thread t owns pixels 4t..4t+3 (contiguous, row-major):
    // row = t>>3, cols cb..cb+3 where cb = (t&7)*4
    const int row = t >> 3;
    const int cb  = (t & 7) << 2;
    const int rm = (row == 0)  ? 0  : row - 1;
    const int rp = (row == 31) ? 31 : row + 1;

    // 3 rows x 6 cols register window (edge-clamped cols)
    float win[3][6];
    #pragma unroll
    for (int w = 0; w < 6; ++w) {
        int c = cb - 1 + w;
        c = c < 0 ? 0 : (c > 31 ? 31 : c);
        win[0][w] = tile[rm][c];
        win[1][w] = tile[row][c];
        win[2][w] = tile[rp][c];
    }

    const float TWO_PI = 6.2831853071795864769f;   // f32(2*pi) == 2*f32(pi)
    const float PI_F   = 3.14159265358979323846f;

    #pragma unroll
    for (int i = 0; i < 4; ++i) {
        float A = win[0][i], B = win[0][i + 1], C = win[0][i + 2];
        float D = win[1][i],                    F = win[1][i + 2];
        float G = win[2][i], H = win[2][i + 1], I = win[2][i + 2];

        // kx = [[-1,0,1],[-2,0,2],[-1,0,1]]/8 ; ky = kx.T ; correlation,
        // pre-scaled taps (products exact), ascending (kh,kw) accumulation.
        float gx = -0.125f * A;
        gx += 0.125f  * C;
        gx += -0.25f  * D;
        gx += 0.25f   * F;
        gx += -0.125f * G;
        gx += 0.125f  * I;

        float gy = -0.125f * A;
        gy += -0.25f  * B;
        gy += -0.125f * C;
        gy += 0.125f  * G;
        gy += 0.25f   * H;
        gy += 0.125f  * I;

        float m1 = gx * gx;
        float m2 = gy * gy;
        float s  = m1 + m2;
        s = s + 1e-8f;
        float mag = sqrtf(s);                      // IEEE sqrt

        float gxe = gx + 1e-8f;
        float at  = (float)atan2((double)gy, (double)gxe);  // CR f32 atan2
        float ori = at + TWO_PI;
        float obig = (36.0f * (ori + PI_F)) / TWO_PI;
        float bo0  = floorf(obig);
        float wo1  = obig - bo0;                   // exact (Sterbenz)

        int bi0 = (int)bo0;
        bi0 = ((bi0 % NBINS) + NBINS) % NBINS;     // true floored mod

        const int px = (t << 2) + i;               // pixel index; word = row, bit = cb+i
        wt0[px] = (1.0f - wo1) * mag;
        wt1[px] = wo1 * mag;
        atomicOr(&bm[row][bi0], 1u << (cb + i));
    }
    __syncthreads();

    // Exact np.add.at replication via bitmap walk (ascending pixel order).
    if (t < NBINS) {
        float acc = 0.0f;
        #pragma unroll 1
        for (int w = 0; w < 32; ++w) {             // w0 pass: bins with b0 == t
            unsigned bits = bm[w][t];
            while (bits) {
                int i = __builtin_ctz(bits);
                bits &= bits - 1;
                acc += wt0[(w << 5) + i];
            }
        }
        const int t2 = (t + NBINS - 1) % NBINS;    // w1 pass: pixels with b0 == t-1
        #pragma unroll 1
        for (int w = 0; w < 32; ++w) {
            unsigned bits = bm[w][t2];
            while (bits) {
                int i = __builtin_ctz(bits);
                bits &= bits - 1;
                acc += wt1[(w << 5) + i];
            }
        }
        hsm[t] = acc * (1.0f / 1024.0f);           // /npix, exact pow2
    }
    __syncthreads();

    if (t == 0) {
        float best = -1.0f; int bi = 0;
        #pragma unroll
        for (int i = 0; i < NBINS; ++i) {
            int im_ = (i == 0)         ? NBINS - 1 : i - 1;
            int ip_ = (i == NBINS - 1) ? 0         : i + 1;
            float s0 = 0.33f * hsm[im_];
            float s1 = 0.34f * hsm[i];
            float s2 = 0.33f * hsm[ip_];
            float sm = (s0 + s1) + s2;             // left-to-right, no FMA
            if (sm > best) { best = sm; bi = i; }  // first-occurrence argmax
        }
        float t1 = TWO_PI * (float)bi;
        float t2 = t1 / 36.0f;
        float t3 = t2 - PI_F;
        out[b] = -t3;
    }
}

extern "C" void kernel_launch(void* const* d_in, const int* in_sizes, int n_in,
                              void* d_out, int out_size, void* d_ws, size_t ws_size,
                              hipStream_t stream) {
    const float* patch = (const float*)d_in[0];
    float* out = (float*)d_out;
    const int B = in_sizes[0] / (PS * PS);   // 65536 patches
    patch_orient_kernel<<<B, 256, 0, stream>>>(patch, out);
}

// Round 4
// 577.020 us; speedup vs baseline: 2.1845x; 1.4805x over previous
//
#include <hip/hip_runtime.h>
#include <math.h>

#pragma clang fp contract(off)

#define NBINS 36
#define PS 32

// One block = one patch. Bit-exact replication of the numpy reference:
//  - conv taps pre-scaled (exact pow2 products), summed ascending (kh,kw)
//  - mag = sqrt((gx*gx + gy*gy) + eps), contraction off
//  - atan2 computed in f64, rounded to f32 (matches np atan2f; absmax 0.0 R2/R3)
//  - histogram: per-bin sequential add chain in pixel order, w0 pass then
//    w1 pass (np.add.at semantics). Round-4: order-preserving counting sort
//    (bitmap ranks) puts each bin's weights contiguous; the 36 chain lanes
//    read sequential runs (3 inst/item) instead of ctz-walking bitmaps
//    (6 inst/item at wave-max popcount + conflict-heavy random gathers).
__global__ __launch_bounds__(256)
void patch_orient_kernel(const float* __restrict__ patches, float* __restrict__ out)
{
    __shared__ __align__(16) float tile[PS][PS];       // 4 KiB
    __shared__ unsigned bm[PS][NBINS];                 // 4.5 KiB  bm[row][bin]
    __shared__ unsigned short pref[PS][NBINS];         // 2.25 KiB word-prefix popcounts
    __shared__ unsigned short cnt[NBINS];
    __shared__ unsigned short start[NBINS];
    __shared__ __align__(16) float s0[1024];           // w0 sorted by (bin, pixel)
    __shared__ __align__(16) float s1[1024];           // w1, same permutation
    __shared__ float hsm[NBINS];

    const int t = threadIdx.x;
    const int b = blockIdx.x;
    const float* p = patches + (size_t)b * (PS * PS);

    #pragma unroll
    for (int i = t; i < PS * NBINS; i += 256) ((unsigned*)bm)[i] = 0u;

    ((float4*)tile)[t] = ((const float4*)p)[t];        // coalesced 4 KiB load
    __syncthreads();

    // thread t owns pixels 4t..4t+3: row = t>>3, cols cb..cb+3
    const int row = t >> 3;
    const int cb  = (t & 7) << 2;
    const int rm  = (row == 0)  ? 0  : row - 1;
    const int rp  = (row == 31) ? 31 : row + 1;

    // 3 rows x 6 cols register window: b128 + 2 edge scalars per row
    float win[3][6];
    {
        const int cl = (cb == 0)  ? 0  : cb - 1;
        const int cr = (cb == 28) ? 31 : cb + 4;
        const int rows[3] = {rm, row, rp};
        #pragma unroll
        for (int r = 0; r < 3; ++r) {
            float4 v = *((const float4*)&tile[rows[r]][cb]);
            win[r][0] = tile[rows[r]][cl];
            win[r][1] = v.x; win[r][2] = v.y; win[r][3] = v.z; win[r][4] = v.w;
            win[r][5] = tile[rows[r]][cr];
        }
    }

    const float TWO_PI = 6.2831853071795864769f;   // f32(2*pi) == 2*f32(pi)
    const float PI_F   = 3.14159265358979323846f;

    float w0r[4], w1r[4];
    int   binr[4];

    #pragma unroll
    for (int i = 0; i < 4; ++i) {
        float A = win[0][i], B = win[0][i + 1], C = win[0][i + 2];
        float D = win[1][i],                    F = win[1][i + 2];
        float G = win[2][i], H = win[2][i + 1], I = win[2][i + 2];

        // pre-scaled taps (exact pow2 products), ascending (kh,kw) order
        float gx = -0.125f * A;
        gx += 0.125f  * C;
        gx += -0.25f  * D;
        gx += 0.25f   * F;
        gx += -0.125f * G;
        gx += 0.125f  * I;

        float gy = -0.125f * A;
        gy += -0.25f  * B;
        gy += -0.125f * C;
        gy += 0.125f  * G;
        gy += 0.25f   * H;
        gy += 0.125f  * I;

        float m1 = gx * gx;
        float m2 = gy * gy;
        float s  = m1 + m2;
        s = s + 1e-8f;
        float mag = sqrtf(s);                      // IEEE sqrt

        float gxe = gx + 1e-8f;
        float at  = (float)atan2((double)gy, (double)gxe);  // CR f32 atan2
        float ori = at + TWO_PI;
        float obig = (36.0f * (ori + PI_F)) / TWO_PI;
        float bo0  = floorf(obig);
        float wo1  = obig - bo0;                   // exact (Sterbenz)

        // bo0 provably in [35, 72]; fold to [0,36) without magic-mul %36
        int bi0 = (int)bo0 - 36;
        if (bi0 < 0)   bi0 += 36;                  // 35 -> 35
        if (bi0 >= 36) bi0 -= 36;                  // 72 -> 0

        w0r[i]  = (1.0f - wo1) * mag;
        w1r[i]  = wo1 * mag;
        binr[i] = bi0;
        atomicOr(&bm[row][bi0], 1u << (cb + i));
    }
    __syncthreads();

    // wave 0: per-bin word-prefix popcounts + counts + bin-start prefix
    if (t < 64) {
        unsigned run = 0;
        if (t < NBINS) {
            #pragma unroll 1
            for (int w = 0; w < PS; ++w) {
                pref[w][t] = (unsigned short)run;
                run += __popc(bm[w][t]);
            }
            cnt[t] = (unsigned short)run;
        }
        // exclusive prefix over bins (wave-wide shfl scan; lanes >=36 hold 0)
        unsigned v = run;
        #pragma unroll
        for (int d = 1; d < 64; d <<= 1) {
            unsigned o = (unsigned)__shfl_up((int)v, d);
            if (t >= d) v += o;
        }
        if (t < NBINS) start[t] = (unsigned short)(v - run);
    }
    __syncthreads();

    // scatter weights from registers into bin-sorted order (stable by pixel)
    #pragma unroll
    for (int i = 0; i < 4; ++i) {
        const int bi = binr[i];
        const unsigned lowmask = (1u << (cb + i)) - 1u;
        const int pos = (int)start[bi] + (int)pref[row][bi]
                      + __popc(bm[row][bi] & lowmask);
        s0[pos] = w0r[i];
        s1[pos] = w1r[i];
    }
    __syncthreads();

    // exact np.add.at chains: bin t = (w0 run of bin t) then (w1 run of bin t-1)
    if (t < NBINS) {
        float acc = 0.0f;
        {
            int st = start[t], en = st + cnt[t];
            #pragma unroll 1
            for (int i = st; i < en; ++i) acc += s0[i];
        }
        {
            int t2 = (t == 0) ? NBINS - 1 : t - 1;
            int st = start[t2], en = st + cnt[t2];
            #pragma unroll 1
            for (int i = st; i < en; ++i) acc += s1[i];
        }
        hsm[t] = acc * (1.0f / 1024.0f);           // /npix, exact pow2
    }
    __syncthreads();

    if (t == 0) {
        float best = -1.0f; int bi = 0;
        #pragma unroll
        for (int i = 0; i < NBINS; ++i) {
            int im_ = (i == 0)         ? NBINS - 1 : i - 1;
            int ip_ = (i == NBINS - 1) ? 0         : i + 1;
            float q0 = 0.33f * hsm[im_];
            float q1 = 0.34f * hsm[i];
            float q2 = 0.33f * hsm[ip_];
            float sm = (q0 + q1) + q2;             // left-to-right, no FMA
            if (sm > best) { best = sm; bi = i; }  // first-occurrence argmax
        }
        float t1 = TWO_PI * (float)bi;
        float t2 = t1 / 36.0f;
        float t3 = t2 - PI_F;
        out[b] = -t3;
    }
}

extern "C" void kernel_launch(void* const* d_in, const int* in_sizes, int n_in,
                              void* d_out, int out_size, void* d_ws, size_t ws_size,
                              hipStream_t stream) {
    const float* patch = (const float*)d_in[0];
    float* out = (float*)d_out;
    const int B = in_sizes[0] / (PS * PS);   // 65536 patches
    patch_orient_kernel<<<B, 256, 0, stream>>>(patch, out);
}

// Round 5
// 532.462 us; speedup vs baseline: 2.3673x; 1.0837x over previous
//
#include <hip/hip_runtime.h>
#include <math.h>

#pragma clang fp contract(off)

#define NBINS 36
#define PS 32

// Slim branchless f64 atan2, rounded to f32. Replaces OCML __ocml_atan2_f64
// (full IEEE div + special-case selects, ~55-60 f64 inst) with ~38 f64 inst:
//  - reduction x = (v - c*u)/(u + c*v), c in {0, 0.5, 1}  -> |x| <= 0.4375
//  - ONE fast division: v_rcp_f64 + 2 Newton + quotient correction (~0.5 ulp)
//  - canonical fdlibm degree-11-in-z minimax poly (err 2^-58 on [0,7/16])
//  - quadrant fixups with hi/lo pi constants
// Total f64 relative error ~2^-50: P(differ from round(true atan2) at f32)
// ~2^-26/sample -> ~1 pixel in all 64M -> argmax unaffected.
__device__ __forceinline__ float atan2_np(float fy, float fx)
{
    const double aT0  =  3.33333333333329318027e-01;
    const double aT1  = -1.99999999998764832476e-01;
    const double aT2  =  1.42857142725034663711e-01;
    const double aT3  = -1.11111104054623557880e-01;
    const double aT4  =  9.09088713343650656196e-02;
    const double aT5  = -7.69187620504482999495e-02;
    const double aT6  =  6.66107313738753120669e-02;
    const double aT7  = -5.83357013379057348645e-02;
    const double aT8  =  4.97687799461593236017e-02;
    const double aT9  = -3.65315727442169155270e-02;
    const double aT10 =  1.62858201153657823623e-02;

    double y = (double)fy, x = (double)fx;
    double ax = fabs(x), ay = fabs(y);
    double u = fmax(ax, ay);
    double v = fmin(ax, ay);

    bool g1 = v >= 0.4375 * u;            // r >= 7/16
    bool g2 = v >= 0.6875 * u;            // r >= 11/16
    double c      = g2 ? 1.0 : (g1 ? 0.5 : 0.0);
    double atc_hi = g2 ? 7.85398163397448278999e-01
                       : (g1 ? 4.63647609000806093515e-01 : 0.0);
    double atc_lo = g2 ? 3.06161699786838301793e-17
                       : (g1 ? 2.26987774529616870924e-17 : 0.0);

    double num = fma(-c, u, v);
    double den = fma(c, v, u);

    double r0 = __builtin_amdgcn_rcp(den);
    r0 = fma(fma(-den, r0, 1.0), r0, r0);
    r0 = fma(fma(-den, r0, 1.0), r0, r0);
    double q0 = num * r0;
    double xq = fma(fma(-den, q0, num), r0, q0);   // ~0.5 ulp quotient

    double z = xq * xq;
    double w = z * z;
    double s1 = z * fma(w, fma(w, fma(w, fma(w, fma(w, aT10, aT8), aT6), aT4), aT2), aT0);
    double s2 = w * fma(w, fma(w, fma(w, fma(w, aT9, aT7), aT5), aT3), aT1);
    double p  = xq * (s1 + s2);
    double res = atc_hi - ((p - atc_lo) - xq);     // angle of (u,v), [0, pi/4+]

    double res2 = (1.57079632679489655800e+00 - res) + 6.12323399573676603587e-17;
    res = (ay > ax) ? res2 : res;                  // angle of (|x|,|y|)
    double res3 = (3.14159265358979311600e+00 - res) + 1.22464679914735317723e-16;
    res = (x < 0.0) ? res3 : res;                  // x<0 half-plane
    res = copysign(res, y);
    return (float)res;
}

// One block = one patch. Bit-exact replication of the numpy reference:
//  - conv taps pre-scaled (exact pow2 products), summed ascending (kh,kw)
//  - mag = sqrt((gx*gx + gy*gy) + eps), contraction off
//  - atan2: slim f64 (above), rounded to f32
//  - histogram: per-bin sequential add chain in pixel order, w0 pass then
//    w1 pass (np.add.at semantics), via order-preserving counting sort
__global__ __launch_bounds__(256)
void patch_orient_kernel(const float* __restrict__ patches, float* __restrict__ out)
{
    __shared__ __align__(16) float tile[PS][PS];       // 4 KiB
    __shared__ unsigned bm[PS][NBINS];                 // 4.5 KiB  bm[row][bin]
    __shared__ unsigned short pref[PS][NBINS];         // 2.25 KiB word-prefix popcounts
    __shared__ unsigned short cnt[NBINS];
    __shared__ unsigned short start[NBINS];
    __shared__ __align__(16) float s0[1024];           // w0 sorted by (bin, pixel)
    __shared__ __align__(16) float s1[1024];           // w1, same permutation
    __shared__ float hsm[NBINS];

    const int t = threadIdx.x;
    const int b = blockIdx.x;
    const float* p = patches + (size_t)b * (PS * PS);

    #pragma unroll
    for (int i = t; i < PS * NBINS; i += 256) ((unsigned*)bm)[i] = 0u;

    ((float4*)tile)[t] = ((const float4*)p)[t];        // coalesced 4 KiB load
    __syncthreads();

    // thread t owns pixels 4t..4t+3: row = t>>3, cols cb..cb+3
    const int row = t >> 3;
    const int cb  = (t & 7) << 2;
    const int rm  = (row == 0)  ? 0  : row - 1;
    const int rp  = (row == 31) ? 31 : row + 1;

    // 3 rows x 6 cols register window: b128 + 2 edge scalars per row
    float win[3][6];
    {
        const int cl = (cb == 0)  ? 0  : cb - 1;
        const int cr = (cb == 28) ? 31 : cb + 4;
        const int rows[3] = {rm, row, rp};
        #pragma unroll
        for (int r = 0; r < 3; ++r) {
            float4 v = *((const float4*)&tile[rows[r]][cb]);
            win[r][0] = tile[rows[r]][cl];
            win[r][1] = v.x; win[r][2] = v.y; win[r][3] = v.z; win[r][4] = v.w;
            win[r][5] = tile[rows[r]][cr];
        }
    }

    const float TWO_PI = 6.2831853071795864769f;   // f32(2*pi) == 2*f32(pi)
    const float PI_F   = 3.14159265358979323846f;

    float w0r[4], w1r[4];
    int   binr[4];

    #pragma unroll
    for (int i = 0; i < 4; ++i) {
        float A = win[0][i], B = win[0][i + 1], C = win[0][i + 2];
        float D = win[1][i],                    F = win[1][i + 2];
        float G = win[2][i], H = win[2][i + 1], I = win[2][i + 2];

        // pre-scaled taps (exact pow2 products), ascending (kh,kw) order
        float gx = -0.125f * A;
        gx += 0.125f  * C;
        gx += -0.25f  * D;
        gx += 0.25f   * F;
        gx += -0.125f * G;
        gx += 0.125f  * I;

        float gy = -0.125f * A;
        gy += -0.25f  * B;
        gy += -0.125f * C;
        gy += 0.125f  * G;
        gy += 0.25f   * H;
        gy += 0.125f  * I;

        float m1 = gx * gx;
        float m2 = gy * gy;
        float s  = m1 + m2;
        s = s + 1e-8f;
        float mag = sqrtf(s);                      // IEEE sqrt

        float gxe = gx + 1e-8f;
        float at  = atan2_np(gy, gxe);
        float ori = at + TWO_PI;
        float obig = (36.0f * (ori + PI_F)) / TWO_PI;
        float bo0  = floorf(obig);
        float wo1  = obig - bo0;                   // exact (Sterbenz)

        // bo0 provably in [35, 72]; fold to [0,36)
        int bi0 = (int)bo0 - 36;
        if (bi0 < 0)   bi0 += 36;                  // 35 -> 35
        if (bi0 >= 36) bi0 -= 36;                  // 72 -> 0

        w0r[i]  = (1.0f - wo1) * mag;
        w1r[i]  = wo1 * mag;
        binr[i] = bi0;
        atomicOr(&bm[row][bi0], 1u << (cb + i));
    }
    __syncthreads();

    // wave 0: per-bin word-prefix popcounts + counts + bin-start prefix
    if (t < 64) {
        unsigned run = 0;
        if (t < NBINS) {
            #pragma unroll 1
            for (int w = 0; w < PS; ++w) {
                pref[w][t] = (unsigned short)run;
                run += __popc(bm[w][t]);
            }
            cnt[t] = (unsigned short)run;
        }
        // exclusive prefix over bins (wave-wide shfl scan; lanes >=36 hold 0)
        unsigned v = run;
        #pragma unroll
        for (int d = 1; d < 64; d <<= 1) {
            unsigned o = (unsigned)__shfl_up((int)v, d);
            if (t >= d) v += o;
        }
        if (t < NBINS) start[t] = (unsigned short)(v - run);
    }
    __syncthreads();

    // scatter weights from registers into bin-sorted order (stable by pixel)
    #pragma unroll
    for (int i = 0; i < 4; ++i) {
        const int bi = binr[i];
        const unsigned lowmask = (1u << (cb + i)) - 1u;
        const int pos = (int)start[bi] + (int)pref[row][bi]
                      + __popc(bm[row][bi] & lowmask);
        s0[pos] = w0r[i];
        s1[pos] = w1r[i];
    }
    __syncthreads();

    // exact np.add.at chains: bin t = (w0 run of bin t) then (w1 run of bin t-1)
    if (t < NBINS) {
        float acc = 0.0f;
        {
            int st = start[t], en = st + cnt[t];
            int i = st;
            for (; i + 1 < en; i += 2) { acc += s0[i]; acc += s0[i + 1]; }
            if (i < en) acc += s0[i];
        }
        {
            int t2 = (t == 0) ? NBINS - 1 : t - 1;
            int st = start[t2], en = st + cnt[t2];
            int i = st;
            for (; i + 1 < en; i += 2) { acc += s1[i]; acc += s1[i + 1]; }
            if (i < en) acc += s1[i];
        }
        hsm[t] = acc * (1.0f / 1024.0f);           // /npix, exact pow2
    }
    __syncthreads();

    if (t == 0) {
        float best = -1.0f; int bi = 0;
        #pragma unroll
        for (int i = 0; i < NBINS; ++i) {
            int im_ = (i == 0)         ? NBINS - 1 : i - 1;
            int ip_ = (i == NBINS - 1) ? 0         : i + 1;
            float q0 = 0.33f * hsm[im_];
            float q1 = 0.34f * hsm[i];
            float q2 = 0.33f * hsm[ip_];
            float sm = (q0 + q1) + q2;             // left-to-right, no FMA
            if (sm > best) { best = sm; bi = i; }  // first-occurrence argmax
        }
        float t1 = TWO_PI * (float)bi;
        float t2 = t1 / 36.0f;
        float t3 = t2 - PI_F;
        out[b] = -t3;
    }
}

extern "C" void kernel_launch(void* const* d_in, const int* in_sizes, int n_in,
                              void* d_out, int out_size, void* d_ws, size_t ws_size,
                              hipStream_t stream) {
    const float* patch = (const float*)d_in[0];
    float* out = (float*)d_out;
    const int B = in_sizes[0] / (PS * PS);   // 65536 patches
    patch_orient_kernel<<<B, 256, 0, stream>>>(patch, out);
}